// Round 24
// baseline (111.808 us; speedup 1.0000x reference)
//
#include <hip/hip_runtime.h>
#include <hip/hip_bf16.h>
#include <math.h>
#include <stdint.h>

#define BATCH 2
#define SEQ   2048
#define EMB   1024
#define HEADS 16
#define DH    64
#define NTOK  (BATCH*SEQ)   // 4096
#define NCOL  (3*EMB)       // 3072: qkv_tok columns (q|k|v, each h-major, d-minor)
#define PLANE (SEQ*DH)      // 131072: per-(b,h) K/V plane elems

typedef float  f32x4  __attribute__((ext_vector_type(4)));
typedef short  bf16x8 __attribute__((ext_vector_type(8)));
typedef short  bf16x4 __attribute__((ext_vector_type(4)));

#define MFMA(a,b,c)   __builtin_amdgcn_mfma_f32_16x16x32_bf16((a),(b),(c),0,0,0)
#define MFMA16(a,b,c) __builtin_amdgcn_mfma_f32_16x16x16bf16_1k((a),(b),(c),0,0,0)

// Q pre-scale: EMB^-0.5 * log2(e)  (softmax runs in log2 domain, exp2 native)
#define SCALE_LOG2E 0.045084220f

__device__ __forceinline__ ushort f2bf(float f) {
    __hip_bfloat16 h = __float2bfloat16(f);
    return __builtin_bit_cast(ushort, h);
}

// async global->LDS, 16B per lane; LDS dest = wave-uniform base + lane*16
__device__ __forceinline__ void gload16(const void* g, void* l) {
    __builtin_amdgcn_global_load_lds(
        (const __attribute__((address_space(1))) void*)g,
        (__attribute__((address_space(3))) void*)l, 16, 0, 0);
}

// ---------------------------------------------------------------------------
// prep: fused {x->bf16, Wo->bf16, W_allT build} in ONE launch.
// ---------------------------------------------------------------------------
#define CONV_N1 (NTOK * EMB / 8)          // 524288
#define CONV_N2 (EMB * EMB / 8)           // 131072
#define CONV_BLOCKS ((CONV_N1 + CONV_N2) / 256)   // 2560
#define PREP_BLOCKS (CONV_BLOCKS + 16 * 48)       // 3328
__global__ __launch_bounds__(256) void prep(
    const float* __restrict__ x,  ushort* __restrict__ xbf,
    const float* __restrict__ Wo, ushort* __restrict__ Wobf,
    const float* __restrict__ Wq, const float* __restrict__ Wk,
    const float* __restrict__ Wv, ushort* __restrict__ WT)
{
    __shared__ float Tf[64][72];
    const int bid = blockIdx.x, tid = threadIdx.x;

    if (bid < CONV_BLOCKS) {
        int i = bid * 256 + tid;
        const float* src; ushort* dst; int k;
        if (i < CONV_N1) { src = x;  dst = xbf;  k = i; }
        else             { src = Wo; dst = Wobf; k = i - CONV_N1; }
        const float4* s = (const float4*)src + (size_t)k * 2;
        float4 a = s[0], b = s[1];
        alignas(16) ushort o[8] = {f2bf(a.x), f2bf(a.y), f2bf(a.z), f2bf(a.w),
                                   f2bf(b.x), f2bf(b.y), f2bf(b.z), f2bf(b.w)};
        *(uint4*)(dst + (size_t)k * 8) = *(const uint4*)o;
        return;
    }

    const int idx = bid - CONV_BLOCKS;
    const int c0 = (idx & 15) * 64;
    const int gy = idx >> 4;                    // m*16 + h
    const int m  = gy >> 4;
    const float* W = (m == 0 ? Wq : (m == 1 ? Wk : Wv)) + (size_t)(gy & 15) * (EMB * DH);

    const int r = tid >> 2, seg = tid & 3;
    const float* src = W + (size_t)(c0 + r) * DH + seg * 16;
#pragma unroll
    for (int j = 0; j < 4; ++j) {
        float4 v = *(const float4*)(src + j * 4);
        int d = seg * 16 + j * 4;
        Tf[d+0][r] = v.x; Tf[d+1][r] = v.y; Tf[d+2][r] = v.z; Tf[d+3][r] = v.w;
    }
    __syncthreads();
    const int d = tid >> 2;
    alignas(16) ushort o[16];
#pragma unroll
    for (int j = 0; j < 16; ++j) o[j] = f2bf(Tf[d][seg * 16 + j]);
    ushort* dst = WT + (size_t)(gy * 64 + d) * EMB + c0 + seg * 16;
    *(uint4*)dst       = *(const uint4*)o;
    *(uint4*)(dst + 8) = *(const uint4*)(o + 8);
}

// ---------------------------------------------------------------------------
// QKV GEMM: [4096][3072] = xbf * W_allT^T.  XCD-aware flat grid of 768.
// Epilogue routing:  Q blocks -> qtok ; K blocks -> Kc[bh][t][d] compact ;
// V blocks -> VT[bh][d][t] transposed.  setprio kept (r21 A/B).
// ---------------------------------------------------------------------------
__global__ __launch_bounds__(256) void qkv_gemm(
    const ushort* __restrict__ A, const ushort* __restrict__ BT,
    ushort* __restrict__ C, ushort* __restrict__ Kc, ushort* __restrict__ VT)
{
    __shared__ char smem[34816];
    ushort* Ab = (ushort*)smem;               // [128][64], swizzled
    ushort* Bb = (ushort*)(smem + 16384);     // [128][64], swizzled
    ushort* Cs = (ushort*)smem;               // [128][136] (epilogue reuse)

    const int bid = blockIdx.x;
    const int t = (bid & 7) * 96 + (bid >> 3);     // XCD-chunked remap (768=8*96)
    const int n0 = (t % 24) * 128, m0 = (t / 24) * 128;
    const int tid = threadIdx.x, lane = tid & 63, wid = tid >> 6;
    const int wr = wid >> 1, wc = wid & 1;
    const int lr = lane >> 3, l15 = lane & 15, lg = lane >> 4;
    const int swz8 = (((lane & 7) ^ lr) & 7) * 8;   // pre-swizzled k-unit

    f32x4 acc[4][4];
#pragma unroll
    for (int i = 0; i < 4; ++i)
#pragma unroll
        for (int j = 0; j < 4; ++j) acc[i][j] = (f32x4){0.f, 0.f, 0.f, 0.f};

    for (int k0 = 0; k0 < EMB; k0 += 64) {
#pragma unroll
        for (int tt = 0; tt < 4; ++tt) {
            int c = wid * 4 + tt;
            int row = c * 8 + lr;
            gload16(A  + (size_t)(m0 + row) * EMB + k0 + swz8, Ab + c * 512);
            gload16(BT + (size_t)(n0 + row) * EMB + k0 + swz8, Bb + c * 512);
        }
        __syncthreads();
        __builtin_amdgcn_s_setprio(1);
#pragma unroll
        for (int ks = 0; ks < 2; ++ks) {
            bf16x8 fa[4], fb[4];
#pragma unroll
            for (int f = 0; f < 4; ++f) {
                int ku = (ks * 4 + lg) ^ (l15 & 7);      // row&7 == l15&7
                fa[f] = *(const bf16x8*)(Ab + (wr * 64 + f * 16 + l15) * 64 + ku * 8);
                fb[f] = *(const bf16x8*)(Bb + (wc * 64 + f * 16 + l15) * 64 + ku * 8);
            }
#pragma unroll
            for (int i = 0; i < 4; ++i)
#pragma unroll
                for (int j = 0; j < 4; ++j)
                    acc[i][j] = MFMA(fa[i], fb[j], acc[i][j]);
        }
        __builtin_amdgcn_s_setprio(0);
        __syncthreads();
    }

    const float sc = (n0 < EMB) ? SCALE_LOG2E : 1.0f;
#pragma unroll
    for (int i = 0; i < 4; ++i) {
        int row = wr * 64 + i * 16 + lg * 4;
#pragma unroll
        for (int j = 0; j < 4; ++j) {
            int col = wc * 64 + j * 16 + l15;
#pragma unroll
            for (int r = 0; r < 4; ++r)
                Cs[(row + r) * 136 + col] = f2bf(acc[i][j][r] * sc);
        }
    }
    __syncthreads();

    const int b = m0 >> 11, t0 = m0 & 2047;
    if (n0 < EMB) {
        // Q blocks: coalesced bf16 store to qtok
#pragma unroll
        for (int it = 0; it < 8; ++it) {
            int c = tid + it * 256;
            int row = c >> 4, off = (c & 15) * 8;
            *(uint4*)(C + (size_t)(m0 + row) * NCOL + n0 + off) =
                *(const uint4*)(Cs + row * 136 + off);
        }
    } else if (n0 < 2 * EMB) {
        // K blocks: compact per-head planes Kc[bh][t][d]
#pragma unroll
        for (int it = 0; it < 8; ++it) {
            int c = tid + it * 256;
            int row = c >> 4, off = (c & 15) * 8;
            int h = ((n0 - EMB) >> 6) + (off >> 6), d0 = off & 63;
            *(uint4*)(Kc + (size_t)(b * HEADS + h) * PLANE
                         + (size_t)(t0 + row) * DH + d0) =
                *(const uint4*)(Cs + row * 136 + off);
        }
    } else {
        // V blocks: write transposed to VT[bh][d][t']
#pragma unroll
        for (int it = 0; it < 8; ++it) {
            int c = tid + it * 256;          // 0..2047
            int col = c & 127;               // 0..127 within tile
            int rg  = c >> 7;                // 0..15 row-group (8 tokens)
            int h = (n0 - 2 * EMB + col) >> 6, d = col & 63;
            alignas(16) ushort tmp[8];
#pragma unroll
            for (int j = 0; j < 8; ++j) tmp[j] = Cs[(rg * 8 + j) * 136 + col];
            *(uint4*)(VT + (size_t)(b * HEADS + h) * PLANE
                          + (size_t)d * SEQ + t0 + rg * 8) = *(const uint4*)tmp;
        }
    }
}

// ---------------------------------------------------------------------------
// MFMA flash attention v11: v10 + PAIRED Q-TILES.  One block processes two
// q-tiles (qtA = 31-pr heavy, qtB = pr) of the same (b,h): K/V staged ONCE
// per kv-tile serves both accumulations (26% fewer stages; 2x compute per
// stage while both active).  B-tile compute predicated wave-uniformly by
// kt <= qtB; barriers uniform (loop bound qtA common to all waves).
// Grid 512 = 16 pairs x 32 bh, heavy-first.  Per-output arithmetic is
// order-identical to v10 -> same absmax.
// ---------------------------------------------------------------------------
__global__ __launch_bounds__(256) void attn_mfma(
    const ushort* __restrict__ C, const ushort* __restrict__ Kc,
    const ushort* __restrict__ VT, ushort* __restrict__ Y)
{
    __shared__ ushort KT[2][64 * 64];     // [buf][kv][d], swizzled
    __shared__ ushort VTl[2][64 * 64];    // [buf][d][kv], swizzled

    const int bid = blockIdx.x;
    const int pr = bid >> 5;              // 0..15, heavy pair first
    const int bh = bid & 31;
    const int qtA = 31 - pr, qtB = pr;    // qtA >= 16 > 15 >= qtB
    const int b = bh >> 4, h = bh & 15;
    const int tid = threadIdx.x, lane = tid & 63, wid = tid >> 6;
    const int l15 = lane & 15, lg = lane >> 4, lr = lane >> 3;
    const int qr0A = qtA * 64 + wid * 16;
    const int qr0B = qtB * 64 + wid * 16;
    const int swz8 = (((lane & 7) ^ lr) & 7) * 8;

    const ushort* Kp = Kc + (size_t)bh * PLANE;
    const ushort* Vp = VT + (size_t)bh * PLANE;

    // Q fragments for both tiles (row = l15, k = ks*32 + lg*8)
    bf16x8 qaA[2], qaB[2];
#pragma unroll
    for (int ks = 0; ks < 2; ++ks) {
        qaA[ks] = *(const bf16x8*)(C + (size_t)(b * SEQ + qr0A + l15) * NCOL
                                     + h * DH + ks * 32 + lg * 8);
        qaB[ks] = *(const bf16x8*)(C + (size_t)(b * SEQ + qr0B + l15) * NCOL
                                     + h * DH + ks * 32 + lg * 8);
    }

    bf16x4 ones4;
#pragma unroll
    for (int j = 0; j < 4; ++j) ones4[j] = (short)0x3F80;   // bf16 1.0

    f32x4 ofA[4], oflA, ofB[4], oflB;
#pragma unroll
    for (int fd = 0; fd < 4; ++fd) {
        ofA[fd] = (f32x4){0.f, 0.f, 0.f, 0.f};
        ofB[fd] = (f32x4){0.f, 0.f, 0.f, 0.f};
    }
    oflA = (f32x4){0.f, 0.f, 0.f, 0.f};
    oflB = (f32x4){0.f, 0.f, 0.f, 0.f};

    const int nkt = qtA + 1;

    // prologue: stage tile 0 into buffer 0
#pragma unroll
    for (int t = 0; t < 2; ++t) {
        int c = wid * 2 + t;
        int row = c * 8 + lr;
        gload16(Kp + (size_t)row * DH + swz8,  KT[0] + c * 512);
        gload16(Vp + (size_t)row * SEQ + swz8, VTl[0] + c * 512);
    }
    __syncthreads();

    for (int kt = 0; kt < nkt; ++kt) {
        const int cur = kt & 1;
        // prefetch next tile into the other buffer (overlaps with compute)
        if (kt + 1 < nkt) {
            const int kv1 = (kt + 1) * 64;
#pragma unroll
            for (int t = 0; t < 2; ++t) {
                int c = wid * 2 + t;
                int row = c * 8 + lr;
                gload16(Kp + (size_t)(kv1 + row) * DH + swz8,  KT[cur ^ 1] + c * 512);
                gload16(Vp + (size_t)row * SEQ + kv1 + swz8,   VTl[cur ^ 1] + c * 512);
            }
        }

        // K fragments for this tile (shared by A and B S^T computations)
        bf16x8 kb[2][4];
#pragma unroll
        for (int ks = 0; ks < 2; ++ks)
#pragma unroll
            for (int fc = 0; fc < 4; ++fc) {
                int row = fc * 16 + l15;
                int ku  = (ks * 4 + lg) ^ (row & 7);
                kb[ks][fc] = *(const bf16x8*)(KT[cur] + row * 64 + ku * 8);
            }

        // ----- tile A (always active) -----
        {
            f32x4 sa[4];
#pragma unroll
            for (int fc = 0; fc < 4; ++fc) sa[fc] = (f32x4){0.f, 0.f, 0.f, 0.f};
#pragma unroll
            for (int ks = 0; ks < 2; ++ks)
#pragma unroll
                for (int fc = 0; fc < 4; ++fc)
                    sa[fc] = MFMA(kb[ks][fc], qaA[ks], sa[fc]);
            if (kt == qtA) {
#pragma unroll
                for (int fc = 0; fc < 4; ++fc)
#pragma unroll
                    for (int r = 0; r < 4; ++r)
                        if (fc * 16 + lg * 4 + r > wid * 16 + l15) sa[fc][r] = -3.0e38f;
            }
            bf16x4 pc[4];
#pragma unroll
            for (int fc = 0; fc < 4; ++fc) {
                uint u0 = (uint)f2bf(exp2f(sa[fc][0]))
                        | ((uint)f2bf(exp2f(sa[fc][1])) << 16);
                uint u1 = (uint)f2bf(exp2f(sa[fc][2]))
                        | ((uint)f2bf(exp2f(sa[fc][3])) << 16);
                uint2 uu = {u0, u1};
                pc[fc] = __builtin_bit_cast(bf16x4, uu);
            }
#pragma unroll
            for (int fc = 0; fc < 4; ++fc) {
                int g = fc * 2 + (lg >> 1);
#pragma unroll
                for (int fd = 0; fd < 4; ++fd) {
                    int vrow = fd * 16 + l15;
                    int vu   = g ^ (vrow & 7);
                    bf16x4 vb = *(const bf16x4*)(VTl[cur] + vrow * 64 + vu * 8 + (lg & 1) * 4);
                    ofA[fd] = MFMA16(pc[fc], vb, ofA[fd]);
                }
                oflA = MFMA16(pc[fc], ones4, oflA);
            }
        }

        // ----- tile B (active while kt <= qtB; wave-uniform predicate) -----
        if (kt <= qtB) {
            f32x4 sa[4];
#pragma unroll
            for (int fc = 0; fc < 4; ++fc) sa[fc] = (f32x4){0.f, 0.f, 0.f, 0.f};
#pragma unroll
            for (int ks = 0; ks < 2; ++ks)
#pragma unroll
                for (int fc = 0; fc < 4; ++fc)
                    sa[fc] = MFMA(kb[ks][fc], qaB[ks], sa[fc]);
            if (kt == qtB) {
#pragma unroll
                for (int fc = 0; fc < 4; ++fc)
#pragma unroll
                    for (int r = 0; r < 4; ++r)
                        if (fc * 16 + lg * 4 + r > wid * 16 + l15) sa[fc][r] = -3.0e38f;
            }
            bf16x4 pc[4];
#pragma unroll
            for (int fc = 0; fc < 4; ++fc) {
                uint u0 = (uint)f2bf(exp2f(sa[fc][0]))
                        | ((uint)f2bf(exp2f(sa[fc][1])) << 16);
                uint u1 = (uint)f2bf(exp2f(sa[fc][2]))
                        | ((uint)f2bf(exp2f(sa[fc][3])) << 16);
                uint2 uu = {u0, u1};
                pc[fc] = __builtin_bit_cast(bf16x4, uu);
            }
#pragma unroll
            for (int fc = 0; fc < 4; ++fc) {
                int g = fc * 2 + (lg >> 1);
#pragma unroll
                for (int fd = 0; fd < 4; ++fd) {
                    int vrow = fd * 16 + l15;
                    int vu   = g ^ (vrow & 7);
                    bf16x4 vb = *(const bf16x4*)(VTl[cur] + vrow * 64 + vu * 8 + (lg & 1) * 4);
                    ofB[fd] = MFMA16(pc[fc], vb, ofB[fd]);
                }
                oflB = MFMA16(pc[fc], ones4, oflB);
            }
        }

        // one barrier per tile: everyone done reading buf[cur] before restage;
        // its vmcnt(0) drain ensures the prefetch landed.
        __syncthreads();
    }

    // normalize + store Y for both tiles (q_local=lg*4+r, d=fd*16+l15)
#pragma unroll
    for (int r = 0; r < 4; ++r) {
        float invA = 1.f / oflA[r];
        float invB = 1.f / oflB[r];
        int rowA = b * SEQ + qr0A + lg * 4 + r;
        int rowB = b * SEQ + qr0B + lg * 4 + r;
#pragma unroll
        for (int fd = 0; fd < 4; ++fd) {
            Y[(size_t)rowA * EMB + h * DH + fd * 16 + l15] = f2bf(ofA[fd][r] * invA);
            Y[(size_t)rowB * EMB + h * DH + fd * 16 + l15] = f2bf(ofB[fd][r] * invB);
        }
    }
}

// ---------------------------------------------------------------------------
// Output projection: out[4096][1024] = Ybf * Wo^T + bo (fp32 out).
// XCD-aware flat grid of 256 (t = (bid&7)*32 + bid>>3).  setprio kept.
// ---------------------------------------------------------------------------
__global__ __launch_bounds__(256) void out_gemm(
    const ushort* __restrict__ A, const ushort* __restrict__ BT,
    const float* __restrict__ bo, float* __restrict__ out)
{
    __shared__ char smem[32768];
    ushort* Ab = (ushort*)smem;
    ushort* Bb = (ushort*)(smem + 16384);

    const int bid = blockIdx.x;
    const int t = (bid & 7) * 32 + (bid >> 3);     // XCD-chunked remap (256=8*32)
    const int n0 = (t % 8) * 128, m0 = (t / 8) * 128;
    const int tid = threadIdx.x, lane = tid & 63, wid = tid >> 6;
    const int wr = wid >> 1, wc = wid & 1;
    const int lr = lane >> 3, l15 = lane & 15, lg = lane >> 4;
    const int swz8 = (((lane & 7) ^ lr) & 7) * 8;

    f32x4 acc[4][4];
#pragma unroll
    for (int i = 0; i < 4; ++i)
#pragma unroll
        for (int j = 0; j < 4; ++j) acc[i][j] = (f32x4){0.f, 0.f, 0.f, 0.f};

    for (int k0 = 0; k0 < EMB; k0 += 64) {
#pragma unroll
        for (int tt = 0; tt < 4; ++tt) {
            int c = wid * 4 + tt;
            int row = c * 8 + lr;
            gload16(A  + (size_t)(m0 + row) * EMB + k0 + swz8, Ab + c * 512);
            gload16(BT + (size_t)(n0 + row) * EMB + k0 + swz8, Bb + c * 512);
        }
        __syncthreads();
        __builtin_amdgcn_s_setprio(1);
#pragma unroll
        for (int ks = 0; ks < 2; ++ks) {
            bf16x8 fa[4], fb[4];
#pragma unroll
            for (int f = 0; f < 4; ++f) {
                int ku = (ks * 4 + lg) ^ (l15 & 7);
                fa[f] = *(const bf16x8*)(Ab + (wr * 64 + f * 16 + l15) * 64 + ku * 8);
                fb[f] = *(const bf16x8*)(Bb + (wc * 64 + f * 16 + l15) * 64 + ku * 8);
            }
#pragma unroll
            for (int i = 0; i < 4; ++i)
#pragma unroll
                for (int j = 0; j < 4; ++j)
                    acc[i][j] = MFMA(fa[i], fb[j], acc[i][j]);
        }
        __builtin_amdgcn_s_setprio(0);
        __syncthreads();
    }

#pragma unroll
    for (int i = 0; i < 4; ++i) {
        int row = m0 + wr * 64 + i * 16 + lg * 4;
#pragma unroll
        for (int j = 0; j < 4; ++j) {
            int col = n0 + wc * 64 + j * 16 + l15;
            float bias = bo[col];
#pragma unroll
            for (int r = 0; r < 4; ++r)
                out[(size_t)(row + r) * EMB + col] = acc[i][j][r] + bias;
        }
    }
}

// ---------------------------------------------------------------------------
extern "C" void kernel_launch(void* const* d_in, const int* in_sizes, int n_in,
                              void* d_out, int out_size, void* d_ws, size_t ws_size,
                              hipStream_t stream)
{
    const float* x  = (const float*)d_in[0];
    const float* Wq = (const float*)d_in[1];
    const float* Wk = (const float*)d_in[2];
    const float* Wv = (const float*)d_in[3];
    const float* Wo = (const float*)d_in[4];
    const float* bo = (const float*)d_in[5];
    float* out = (float*)d_out;

    char* ws = (char*)d_ws;
    ushort* xbf  = (ushort*)(ws);                // [4096][1024]  8 MB
    ushort* WT   = (ushort*)(ws + (8  << 20));   // [3072][1024]  6 MB
    ushort* Wobf = (ushort*)(ws + (14 << 20));   // [1024][1024]  2 MB
    ushort* qtok = (ushort*)(ws + (16 << 20));   // [4096][3072] 24 MB (Q cols only)
    ushort* VT   = (ushort*)(ws + (40 << 20));   // [32][64][2048] 8 MB
    ushort* Ybf  = (ushort*)(ws + (48 << 20));   // [4096][1024]  8 MB
    ushort* Kc   = (ushort*)(ws + (56 << 20));   // [32][2048][64] 8 MB

    prep<<<PREP_BLOCKS, 256, 0, stream>>>(x, xbf, Wo, Wobf, Wq, Wk, Wv, WT);
    qkv_gemm<<<768, 256, 0, stream>>>(xbf, WT, qtok, Kc, VT);
    attn_mfma<<<512, 256, 0, stream>>>(qtok, Kc, VT, Ybf);
    out_gemm<<<256, 256, 0, stream>>>(Ybf, Wobf, bo, out);
}

// Round 25
// 106.896 us; speedup vs baseline: 1.0459x; 1.0459x over previous
//
#include <hip/hip_runtime.h>
#include <hip/hip_bf16.h>
#include <math.h>
#include <stdint.h>

#define BATCH 2
#define SEQ   2048
#define EMB   1024
#define HEADS 16
#define DH    64
#define NTOK  (BATCH*SEQ)   // 4096
#define NCOL  (3*EMB)       // 3072: qkv_tok columns (q|k|v, each h-major, d-minor)
#define PLANE (SEQ*DH)      // 131072: per-(b,h) K/V plane elems

typedef float  f32x4  __attribute__((ext_vector_type(4)));
typedef short  bf16x8 __attribute__((ext_vector_type(8)));
typedef short  bf16x4 __attribute__((ext_vector_type(4)));

#define MFMA(a,b,c)   __builtin_amdgcn_mfma_f32_16x16x32_bf16((a),(b),(c),0,0,0)
#define MFMA16(a,b,c) __builtin_amdgcn_mfma_f32_16x16x16bf16_1k((a),(b),(c),0,0,0)

// Q pre-scale: EMB^-0.5 * log2(e)  (softmax runs in log2 domain, exp2 native)
#define SCALE_LOG2E 0.045084220f

__device__ __forceinline__ ushort f2bf(float f) {
    __hip_bfloat16 h = __float2bfloat16(f);
    return __builtin_bit_cast(ushort, h);
}

// async global->LDS, 16B per lane; LDS dest = wave-uniform base + lane*16
__device__ __forceinline__ void gload16(const void* g, void* l) {
    __builtin_amdgcn_global_load_lds(
        (const __attribute__((address_space(1))) void*)g,
        (__attribute__((address_space(3))) void*)l, 16, 0, 0);
}

// ---------------------------------------------------------------------------
// prep: fused {x->bf16, Wo->bf16, W_allT build} in ONE launch.
// ---------------------------------------------------------------------------
#define CONV_N1 (NTOK * EMB / 8)          // 524288
#define CONV_N2 (EMB * EMB / 8)           // 131072
#define CONV_BLOCKS ((CONV_N1 + CONV_N2) / 256)   // 2560
#define PREP_BLOCKS (CONV_BLOCKS + 16 * 48)       // 3328
__global__ __launch_bounds__(256) void prep(
    const float* __restrict__ x,  ushort* __restrict__ xbf,
    const float* __restrict__ Wo, ushort* __restrict__ Wobf,
    const float* __restrict__ Wq, const float* __restrict__ Wk,
    const float* __restrict__ Wv, ushort* __restrict__ WT)
{
    __shared__ float Tf[64][72];
    const int bid = blockIdx.x, tid = threadIdx.x;

    if (bid < CONV_BLOCKS) {
        int i = bid * 256 + tid;
        const float* src; ushort* dst; int k;
        if (i < CONV_N1) { src = x;  dst = xbf;  k = i; }
        else             { src = Wo; dst = Wobf; k = i - CONV_N1; }
        const float4* s = (const float4*)src + (size_t)k * 2;
        float4 a = s[0], b = s[1];
        alignas(16) ushort o[8] = {f2bf(a.x), f2bf(a.y), f2bf(a.z), f2bf(a.w),
                                   f2bf(b.x), f2bf(b.y), f2bf(b.z), f2bf(b.w)};
        *(uint4*)(dst + (size_t)k * 8) = *(const uint4*)o;
        return;
    }

    const int idx = bid - CONV_BLOCKS;
    const int c0 = (idx & 15) * 64;
    const int gy = idx >> 4;                    // m*16 + h
    const int m  = gy >> 4;
    const float* W = (m == 0 ? Wq : (m == 1 ? Wk : Wv)) + (size_t)(gy & 15) * (EMB * DH);

    const int r = tid >> 2, seg = tid & 3;
    const float* src = W + (size_t)(c0 + r) * DH + seg * 16;
#pragma unroll
    for (int j = 0; j < 4; ++j) {
        float4 v = *(const float4*)(src + j * 4);
        int d = seg * 16 + j * 4;
        Tf[d+0][r] = v.x; Tf[d+1][r] = v.y; Tf[d+2][r] = v.z; Tf[d+3][r] = v.w;
    }
    __syncthreads();
    const int d = tid >> 2;
    alignas(16) ushort o[16];
#pragma unroll
    for (int j = 0; j < 16; ++j) o[j] = f2bf(Tf[d][seg * 16 + j]);
    ushort* dst = WT + (size_t)(gy * 64 + d) * EMB + c0 + seg * 16;
    *(uint4*)dst       = *(const uint4*)o;
    *(uint4*)(dst + 8) = *(const uint4*)(o + 8);
}

// ---------------------------------------------------------------------------
// QKV GEMM: [4096][3072] = xbf * W_allT^T.  XCD-aware flat grid of 768.
// Epilogue routing:  Q blocks -> qtok ; K blocks -> Kc[bh][t][d] compact ;
// V blocks -> VT[bh][d][t] transposed.  setprio kept (r21 A/B).
// ---------------------------------------------------------------------------
__global__ __launch_bounds__(256) void qkv_gemm(
    const ushort* __restrict__ A, const ushort* __restrict__ BT,
    ushort* __restrict__ C, ushort* __restrict__ Kc, ushort* __restrict__ VT)
{
    __shared__ char smem[34816];
    ushort* Ab = (ushort*)smem;               // [128][64], swizzled
    ushort* Bb = (ushort*)(smem + 16384);     // [128][64], swizzled
    ushort* Cs = (ushort*)smem;               // [128][136] (epilogue reuse)

    const int bid = blockIdx.x;
    const int t = (bid & 7) * 96 + (bid >> 3);     // XCD-chunked remap (768=8*96)
    const int n0 = (t % 24) * 128, m0 = (t / 24) * 128;
    const int tid = threadIdx.x, lane = tid & 63, wid = tid >> 6;
    const int wr = wid >> 1, wc = wid & 1;
    const int lr = lane >> 3, l15 = lane & 15, lg = lane >> 4;
    const int swz8 = (((lane & 7) ^ lr) & 7) * 8;   // pre-swizzled k-unit

    f32x4 acc[4][4];
#pragma unroll
    for (int i = 0; i < 4; ++i)
#pragma unroll
        for (int j = 0; j < 4; ++j) acc[i][j] = (f32x4){0.f, 0.f, 0.f, 0.f};

    for (int k0 = 0; k0 < EMB; k0 += 64) {
#pragma unroll
        for (int tt = 0; tt < 4; ++tt) {
            int c = wid * 4 + tt;
            int row = c * 8 + lr;
            gload16(A  + (size_t)(m0 + row) * EMB + k0 + swz8, Ab + c * 512);
            gload16(BT + (size_t)(n0 + row) * EMB + k0 + swz8, Bb + c * 512);
        }
        __syncthreads();
        __builtin_amdgcn_s_setprio(1);
#pragma unroll
        for (int ks = 0; ks < 2; ++ks) {
            bf16x8 fa[4], fb[4];
#pragma unroll
            for (int f = 0; f < 4; ++f) {
                int ku = (ks * 4 + lg) ^ (l15 & 7);      // row&7 == l15&7
                fa[f] = *(const bf16x8*)(Ab + (wr * 64 + f * 16 + l15) * 64 + ku * 8);
                fb[f] = *(const bf16x8*)(Bb + (wc * 64 + f * 16 + l15) * 64 + ku * 8);
            }
#pragma unroll
            for (int i = 0; i < 4; ++i)
#pragma unroll
                for (int j = 0; j < 4; ++j)
                    acc[i][j] = MFMA(fa[i], fb[j], acc[i][j]);
        }
        __builtin_amdgcn_s_setprio(0);
        __syncthreads();
    }

    const float sc = (n0 < EMB) ? SCALE_LOG2E : 1.0f;
#pragma unroll
    for (int i = 0; i < 4; ++i) {
        int row = wr * 64 + i * 16 + lg * 4;
#pragma unroll
        for (int j = 0; j < 4; ++j) {
            int col = wc * 64 + j * 16 + l15;
#pragma unroll
            for (int r = 0; r < 4; ++r)
                Cs[(row + r) * 136 + col] = f2bf(acc[i][j][r] * sc);
        }
    }
    __syncthreads();

    const int b = m0 >> 11, t0 = m0 & 2047;
    if (n0 < EMB) {
        // Q blocks: coalesced bf16 store to qtok
#pragma unroll
        for (int it = 0; it < 8; ++it) {
            int c = tid + it * 256;
            int row = c >> 4, off = (c & 15) * 8;
            *(uint4*)(C + (size_t)(m0 + row) * NCOL + n0 + off) =
                *(const uint4*)(Cs + row * 136 + off);
        }
    } else if (n0 < 2 * EMB) {
        // K blocks: compact per-head planes Kc[bh][t][d]
#pragma unroll
        for (int it = 0; it < 8; ++it) {
            int c = tid + it * 256;
            int row = c >> 4, off = (c & 15) * 8;
            int h = ((n0 - EMB) >> 6) + (off >> 6), d0 = off & 63;
            *(uint4*)(Kc + (size_t)(b * HEADS + h) * PLANE
                         + (size_t)(t0 + row) * DH + d0) =
                *(const uint4*)(Cs + row * 136 + off);
        }
    } else {
        // V blocks: write transposed to VT[bh][d][t']
#pragma unroll
        for (int it = 0; it < 8; ++it) {
            int c = tid + it * 256;          // 0..2047
            int col = c & 127;               // 0..127 within tile
            int rg  = c >> 7;                // 0..15 row-group (8 tokens)
            int h = (n0 - 2 * EMB + col) >> 6, d = col & 63;
            alignas(16) ushort tmp[8];
#pragma unroll
            for (int j = 0; j < 8; ++j) tmp[j] = Cs[(rg * 8 + j) * 136 + col];
            *(uint4*)(VT + (size_t)(b * HEADS + h) * PLANE
                          + (size_t)d * SEQ + t0 + rg * 8) = *(const uint4*)tmp;
        }
    }
}

// ---------------------------------------------------------------------------
// MFMA flash attention v10 (round-23 config — best measured).
// Swapped QK^T + in-register P + K=16 PV:
//   S^T = MFMA(K, Q): C-layout col=l15=q, row=lg*4+r=kv -> each lane holds
//   P[q=l15][kv=fc*16+lg*4+r], which is EXACTLY the A-fragment layout of
//   mfma_f32_16x16x16_bf16.  P never touches LDS.  Ones-column MFMA gives
//   the denominator.  QBLK=64 (4 waves x 16 q-rows), heavy-first grid 1024
//   (4 blocks/CU — many small independent blocks is the proven optimum;
//   wide/paired variants all regressed: r10, r12, r24).
// ---------------------------------------------------------------------------
__global__ __launch_bounds__(256) void attn_mfma(
    const ushort* __restrict__ C, const ushort* __restrict__ Kc,
    const ushort* __restrict__ VT, ushort* __restrict__ Y)
{
    __shared__ ushort KT[2][64 * 64];     // [buf][kv][d], swizzled
    __shared__ ushort VTl[2][64 * 64];    // [buf][d][kv], swizzled

    const int bid = blockIdx.x;
    const int qt = 31 - (bid >> 5);       // heavy blocks dispatch first
    const int bh = bid & 31;
    const int b = bh >> 4, h = bh & 15;
    const int tid = threadIdx.x, lane = tid & 63, wid = tid >> 6;
    const int l15 = lane & 15, lg = lane >> 4, lr = lane >> 3;
    const int qr0 = qt * 64 + wid * 16;
    const int swz8 = (((lane & 7) ^ lr) & 7) * 8;

    const ushort* Kp = Kc + (size_t)bh * PLANE;
    const ushort* Vp = VT + (size_t)bh * PLANE;

    // Q fragments (row = l15, k = ks*32 + lg*8), pre-scaled by log2e/32
    bf16x8 qa[2];
#pragma unroll
    for (int ks = 0; ks < 2; ++ks)
        qa[ks] = *(const bf16x8*)(C + (size_t)(b * SEQ + qr0 + l15) * NCOL
                                    + h * DH + ks * 32 + lg * 8);

    bf16x4 ones4;
#pragma unroll
    for (int j = 0; j < 4; ++j) ones4[j] = (short)0x3F80;   // bf16 1.0

    f32x4 of[4], ofl;
#pragma unroll
    for (int fd = 0; fd < 4; ++fd) of[fd] = (f32x4){0.f, 0.f, 0.f, 0.f};
    ofl = (f32x4){0.f, 0.f, 0.f, 0.f};

    const int nkt = qt + 1;

    // prologue: stage tile 0 into buffer 0
#pragma unroll
    for (int t = 0; t < 2; ++t) {
        int c = wid * 2 + t;
        int row = c * 8 + lr;
        gload16(Kp + (size_t)row * DH + swz8,  KT[0] + c * 512);
        gload16(Vp + (size_t)row * SEQ + swz8, VTl[0] + c * 512);
    }
    __syncthreads();

    for (int kt = 0; kt < nkt; ++kt) {
        const int cur = kt & 1;
        // prefetch next tile into the other buffer (overlaps with compute)
        if (kt + 1 < nkt) {
            const int kv1 = (kt + 1) * 64;
#pragma unroll
            for (int t = 0; t < 2; ++t) {
                int c = wid * 2 + t;
                int row = c * 8 + lr;
                gload16(Kp + (size_t)(kv1 + row) * DH + swz8,  KT[cur ^ 1] + c * 512);
                gload16(Vp + (size_t)row * SEQ + kv1 + swz8,   VTl[cur ^ 1] + c * 512);
            }
        }

        // S^T = K Q  (64 kv x 16 q): A=K frag (row=kv), B=Q frag (col=q)
        f32x4 sa[4];
#pragma unroll
        for (int fc = 0; fc < 4; ++fc) sa[fc] = (f32x4){0.f, 0.f, 0.f, 0.f};
#pragma unroll
        for (int ks = 0; ks < 2; ++ks) {
#pragma unroll
            for (int fc = 0; fc < 4; ++fc) {
                int row = fc * 16 + l15;
                int ku  = (ks * 4 + lg) ^ (row & 7);
                bf16x8 kb = *(const bf16x8*)(KT[cur] + row * 64 + ku * 8);
                sa[fc] = MFMA(kb, qa[ks], sa[fc]);   // swapped operands
            }
        }
        // causal mask on S^T: element (kv=kv0+fc*16+lg*4+r, q=qr0+l15);
        // only the diagonal tile needs it (kv0 = qt*64, qr0-kv0 = wid*16)
        if (kt == qt) {
#pragma unroll
            for (int fc = 0; fc < 4; ++fc) {
#pragma unroll
                for (int r = 0; r < 4; ++r)
                    if (fc * 16 + lg * 4 + r > wid * 16 + l15) sa[fc][r] = -3.0e38f;
            }
        }

        // P = exp2(S^T) packed in-register: pc[fc] is the K=16 A-fragment
        bf16x4 pc[4];
#pragma unroll
        for (int fc = 0; fc < 4; ++fc) {
            uint u0 = (uint)f2bf(exp2f(sa[fc][0]))
                    | ((uint)f2bf(exp2f(sa[fc][1])) << 16);
            uint u1 = (uint)f2bf(exp2f(sa[fc][2]))
                    | ((uint)f2bf(exp2f(sa[fc][3])) << 16);
            uint2 uu = {u0, u1};
            pc[fc] = __builtin_bit_cast(bf16x4, uu);
        }

        // O += P V via K=16 MFMAs; V B-frag = 4 consecutive kv of a VTl row
        // (global unit g=fc*2+(lg>>1), LDS unit g^(vrow&7), sub (lg&1)*4)
#pragma unroll
        for (int fc = 0; fc < 4; ++fc) {
            int g = fc * 2 + (lg >> 1);
#pragma unroll
            for (int fd = 0; fd < 4; ++fd) {
                int vrow = fd * 16 + l15;
                int vu   = g ^ (vrow & 7);
                bf16x4 vb = *(const bf16x4*)(VTl[cur] + vrow * 64 + vu * 8 + (lg & 1) * 4);
                of[fd] = MFMA16(pc[fc], vb, of[fd]);
            }
            ofl = MFMA16(pc[fc], ones4, ofl);
        }

        // one barrier per tile: everyone done reading buf[cur] before restage;
        // its vmcnt(0) drain ensures the prefetch landed.
        __syncthreads();
    }

    // normalize + store Y (concat-head, bf16); q_local=lg*4+r, d=fd*16+l15
#pragma unroll
    for (int r = 0; r < 4; ++r) {
        float inv = 1.f / ofl[r];
        int row = b * SEQ + qr0 + lg * 4 + r;
#pragma unroll
        for (int fd = 0; fd < 4; ++fd)
            Y[(size_t)row * EMB + h * DH + fd * 16 + l15] = f2bf(of[fd][r] * inv);
    }
}

// ---------------------------------------------------------------------------
// Output projection: out[4096][1024] = Ybf * Wo^T + bo (fp32 out).
// XCD-aware flat grid of 256 (t = (bid&7)*32 + bid>>3).  setprio kept.
// ---------------------------------------------------------------------------
__global__ __launch_bounds__(256) void out_gemm(
    const ushort* __restrict__ A, const ushort* __restrict__ BT,
    const float* __restrict__ bo, float* __restrict__ out)
{
    __shared__ char smem[32768];
    ushort* Ab = (ushort*)smem;
    ushort* Bb = (ushort*)(smem + 16384);

    const int bid = blockIdx.x;
    const int t = (bid & 7) * 32 + (bid >> 3);     // XCD-chunked remap (256=8*32)
    const int n0 = (t % 8) * 128, m0 = (t / 8) * 128;
    const int tid = threadIdx.x, lane = tid & 63, wid = tid >> 6;
    const int wr = wid >> 1, wc = wid & 1;
    const int lr = lane >> 3, l15 = lane & 15, lg = lane >> 4;
    const int swz8 = (((lane & 7) ^ lr) & 7) * 8;

    f32x4 acc[4][4];
#pragma unroll
    for (int i = 0; i < 4; ++i)
#pragma unroll
        for (int j = 0; j < 4; ++j) acc[i][j] = (f32x4){0.f, 0.f, 0.f, 0.f};

    for (int k0 = 0; k0 < EMB; k0 += 64) {
#pragma unroll
        for (int tt = 0; tt < 4; ++tt) {
            int c = wid * 4 + tt;
            int row = c * 8 + lr;
            gload16(A  + (size_t)(m0 + row) * EMB + k0 + swz8, Ab + c * 512);
            gload16(BT + (size_t)(n0 + row) * EMB + k0 + swz8, Bb + c * 512);
        }
        __syncthreads();
        __builtin_amdgcn_s_setprio(1);
#pragma unroll
        for (int ks = 0; ks < 2; ++ks) {
            bf16x8 fa[4], fb[4];
#pragma unroll
            for (int f = 0; f < 4; ++f) {
                int ku = (ks * 4 + lg) ^ (l15 & 7);
                fa[f] = *(const bf16x8*)(Ab + (wr * 64 + f * 16 + l15) * 64 + ku * 8);
                fb[f] = *(const bf16x8*)(Bb + (wc * 64 + f * 16 + l15) * 64 + ku * 8);
            }
#pragma unroll
            for (int i = 0; i < 4; ++i)
#pragma unroll
                for (int j = 0; j < 4; ++j)
                    acc[i][j] = MFMA(fa[i], fb[j], acc[i][j]);
        }
        __builtin_amdgcn_s_setprio(0);
        __syncthreads();
    }

#pragma unroll
    for (int i = 0; i < 4; ++i) {
        int row = m0 + wr * 64 + i * 16 + lg * 4;
#pragma unroll
        for (int j = 0; j < 4; ++j) {
            int col = n0 + wc * 64 + j * 16 + l15;
            float bias = bo[col];
#pragma unroll
            for (int r = 0; r < 4; ++r)
                out[(size_t)(row + r) * EMB + col] = acc[i][j][r] + bias;
        }
    }
}

// ---------------------------------------------------------------------------
extern "C" void kernel_launch(void* const* d_in, const int* in_sizes, int n_in,
                              void* d_out, int out_size, void* d_ws, size_t ws_size,
                              hipStream_t stream)
{
    const float* x  = (const float*)d_in[0];
    const float* Wq = (const float*)d_in[1];
    const float* Wk = (const float*)d_in[2];
    const float* Wv = (const float*)d_in[3];
    const float* Wo = (const float*)d_in[4];
    const float* bo = (const float*)d_in[5];
    float* out = (float*)d_out;

    char* ws = (char*)d_ws;
    ushort* xbf  = (ushort*)(ws);                // [4096][1024]  8 MB
    ushort* WT   = (ushort*)(ws + (8  << 20));   // [3072][1024]  6 MB
    ushort* Wobf = (ushort*)(ws + (14 << 20));   // [1024][1024]  2 MB
    ushort* qtok = (ushort*)(ws + (16 << 20));   // [4096][3072] 24 MB (Q cols only)
    ushort* VT   = (ushort*)(ws + (40 << 20));   // [32][64][2048] 8 MB
    ushort* Ybf  = (ushort*)(ws + (48 << 20));   // [4096][1024]  8 MB
    ushort* Kc   = (ushort*)(ws + (56 << 20));   // [32][2048][64] 8 MB

    prep<<<PREP_BLOCKS, 256, 0, stream>>>(x, xbf, Wo, Wobf, Wq, Wk, Wv, WT);
    qkv_gemm<<<768, 256, 0, stream>>>(xbf, WT, qtok, Kc, VT);
    attn_mfma<<<1024, 256, 0, stream>>>(qtok, Kc, VT, Ybf);
    out_gemm<<<256, 256, 0, stream>>>(Ybf, Wobf, bo, out);
}